// Round 1
// baseline (211.623 us; speedup 1.0000x reference)
//
#include <hip/hip_runtime.h>
#include <math.h>

#define H_IMG 128
#define W_IMG 128
#define N_G   1024
#define F_DIM 512
#define O_DIM 512
#define PIX   (H_IMG*W_IMG)        // 16384
#define FEAT_OFF 49152             // 3*PIX
#define RAD_OFF  (49152 + 512*16384)

// ---------------------------------------------------------------------------
// Kernel 1: per-gaussian preprocessing (projection, conic, radii)
// ---------------------------------------------------------------------------
__global__ void prep_kernel(const float* __restrict__ means,
                            const float* __restrict__ opac,
                            const float* __restrict__ scales,
                            const float* __restrict__ rots,
                            const float* __restrict__ view,
                            const float* __restrict__ proj,
                            float* __restrict__ params8,
                            float* __restrict__ radii_out)
{
    int n = blockIdx.x * blockDim.x + threadIdx.x;
    if (n >= N_G) return;

    float x = means[3*n], y = means[3*n+1], z = means[3*n+2];
    // row-vector times matrix (jnp: ph @ V)
    float pv0 = x*view[0] + y*view[4] + z*view[8]  + view[12];
    float pv1 = x*view[1] + y*view[5] + z*view[9]  + view[13];
    float pv2 = x*view[2] + y*view[6] + z*view[10] + view[14];
    float ph0 = x*proj[0] + y*proj[4] + z*proj[8]  + proj[12];
    float ph1 = x*proj[1] + y*proj[5] + z*proj[9]  + proj[13];
    float phw = x*proj[3] + y*proj[7] + z*proj[11] + proj[15];
    float denom = phw + 1e-7f;
    float pp0 = ph0/denom, pp1 = ph1/denom;
    float depth = pv2;

    float qr=rots[4*n], qx=rots[4*n+1], qy=rots[4*n+2], qz=rots[4*n+3];
    float qn = sqrtf(qr*qr+qx*qx+qy*qy+qz*qz);
    qr/=qn; qx/=qn; qy/=qn; qz/=qn;
    float R00=1.f-2.f*(qy*qy+qz*qz), R01=2.f*(qx*qy-qr*qz), R02=2.f*(qx*qz+qr*qy);
    float R10=2.f*(qx*qy+qr*qz), R11=1.f-2.f*(qx*qx+qz*qz), R12=2.f*(qy*qz-qr*qx);
    float R20=2.f*(qx*qz-qr*qy), R21=2.f*(qy*qz+qr*qx), R22=1.f-2.f*(qx*qx+qy*qy);
    float s0=scales[3*n], s1=scales[3*n+1], s2=scales[3*n+2];
    float M00=R00*s0, M01=R01*s1, M02=R02*s2;
    float M10=R10*s0, M11=R11*s1, M12=R12*s2;
    float M20=R20*s0, M21=R21*s1, M22=R22*s2;
    float c00=M00*M00+M01*M01+M02*M02;
    float c01=M00*M10+M01*M11+M02*M12;
    float c02=M00*M20+M01*M21+M02*M22;
    float c11=M10*M10+M11*M11+M12*M12;
    float c12=M10*M20+M11*M21+M12*M22;
    float c22=M20*M20+M21*M21+M22*M22;

    const float fx=128.f, fy=128.f;
    float tz = pv2;
    float txz = fminf(fmaxf(pv0/tz, -0.65f), 0.65f) * tz;
    float tyz = fminf(fmaxf(pv1/tz, -0.65f), 0.65f) * tz;
    float J00 = fx/tz,  J02 = -fx*txz/(tz*tz);
    float J11 = fy/tz,  J12 = -fy*tyz/(tz*tz);
    // T = J @ view[:3,:3]^T  ->  T[a][b] = sum_c J[a][c]*view[b*4+c]
    float T00=J00*view[0] + J02*view[2];
    float T01=J00*view[4] + J02*view[6];
    float T02=J00*view[8] + J02*view[10];
    float T10=J11*view[1] + J12*view[2];
    float T11=J11*view[5] + J12*view[6];
    float T12=J11*view[9] + J12*view[10];
    // cov2D = T cov3D T^T
    float u0 = T00*c00 + T01*c01 + T02*c02;
    float u1 = T00*c01 + T01*c11 + T02*c12;
    float u2 = T00*c02 + T01*c12 + T02*c22;
    float v0 = T10*c00 + T11*c01 + T12*c02;
    float v1 = T10*c01 + T11*c11 + T12*c12;
    float v2 = T10*c02 + T11*c12 + T12*c22;
    float a00 = u0*T00 + u1*T01 + u2*T02 + 0.3f;
    float a01 = u0*T10 + u1*T11 + u2*T12;
    float a11 = v0*T10 + v1*T11 + v2*T12 + 0.3f;

    float det = a00*a11 - a01*a01;
    float dsafe = (det==0.f) ? 1.f : det;
    float inv = 1.f/dsafe;
    float con0 =  a11*inv, con1 = -a01*inv, con2 = a00*inv;
    float mid = 0.5f*(a00+a11);
    float lam1 = mid + sqrtf(fmaxf(0.1f, mid*mid - det));
    int irad = (int)ceilf(3.f*sqrtf(lam1));
    float pxc = ((pp0+1.f)*128.f - 1.f)*0.5f;
    float pyc = ((pp1+1.f)*128.f - 1.f)*0.5f;
    bool valid = (depth > 0.2f) && (det != 0.f);

    radii_out[n] = valid ? (float)irad : 0.f;
    float* p = params8 + 8*n;
    p[0]=pxc; p[1]=pyc; p[2]=con0; p[3]=con1; p[4]=con2;
    p[5]=opac[n]; p[6]=depth; p[7]= valid ? 1.f : 0.f;
}

// ---------------------------------------------------------------------------
// Kernel 2: rank sort (stable argsort by depth, tie-break by index)
// ---------------------------------------------------------------------------
__global__ void rank_kernel(const float* __restrict__ params8, int* __restrict__ order)
{
    __shared__ float d[N_G];
    int t = threadIdx.x;
    for (int i = t; i < N_G; i += 256) d[i] = params8[8*i+6];
    __syncthreads();
    int n = blockIdx.x*256 + t;
    float dn = d[n];
    int r = 0;
    for (int m = 0; m < N_G; ++m) {
        float dm = d[m];
        r += (dm < dn) || (dm == dn && m < n);
    }
    order[r] = n;
}

// ---------------------------------------------------------------------------
// Kernel 3: pack params/colors into sorted order
// ---------------------------------------------------------------------------
__global__ void pack_kernel(const float* __restrict__ params8,
                            const float* __restrict__ colors,
                            const int* __restrict__ order,
                            float* __restrict__ psort, float* __restrict__ csort)
{
    int k = blockIdx.x*256 + threadIdx.x;
    if (k >= N_G) return;
    int n = order[k];
    #pragma unroll
    for (int j = 0; j < 8; ++j) psort[8*k+j] = params8[8*n+j];
    csort[4*k+0] = colors[3*n+0];
    csort[4*k+1] = colors[3*n+1];
    csort[4*k+2] = colors[3*n+2];
    csort[4*k+3] = 0.f;
}

// ---------------------------------------------------------------------------
// Kernel 4: G[k][o] = sum_f S[order[k],f] * conv_w[o,f]   (0.27 GF)
// ---------------------------------------------------------------------------
__global__ __launch_bounds__(256) void gmat_kernel(const float* __restrict__ S,
                                                   const float* __restrict__ Wm,
                                                   const int* __restrict__ order,
                                                   float* __restrict__ Gv)
{
    __shared__ float St[16][33];
    __shared__ float Wt[16][33];
    int tx = threadIdx.x, ty = threadIdx.y;
    int n0 = blockIdx.x*16, o0 = blockIdx.y*16;
    int srow = order[n0+ty];
    float acc = 0.f;
    for (int f0 = 0; f0 < F_DIM; f0 += 32) {
        St[ty][tx]    = S[(size_t)srow*F_DIM + f0+tx];
        St[ty][tx+16] = S[(size_t)srow*F_DIM + f0+tx+16];
        Wt[ty][tx]    = Wm[(size_t)(o0+ty)*F_DIM + f0+tx];
        Wt[ty][tx+16] = Wm[(size_t)(o0+ty)*F_DIM + f0+tx+16];
        __syncthreads();
        #pragma unroll
        for (int f = 0; f < 32; ++f) acc += St[ty][f]*Wt[tx][f];
        __syncthreads();
    }
    Gv[(size_t)(n0+ty)*O_DIM + o0+tx] = acc;
}

// ---------------------------------------------------------------------------
// Kernel 5: fused compositing + feature GEMM + color
//   block = 512 threads, tile = 64 consecutive pixels (half image row)
//   w-compute: thread = (pixel pi 0..63, group grp 0..7 of 8 gaussians)
//   GEMM:      thread = (pixel pair pq 0..31, output group og 0..15 of 32)
// ---------------------------------------------------------------------------
__global__ __launch_bounds__(512) void composite_kernel(
    const float* __restrict__ psort, const float* __restrict__ csort,
    const float* __restrict__ Gv, const float* __restrict__ conv_b,
    const float* __restrict__ bg, float* __restrict__ out)
{
    __shared__ float pg[64][8];
    __shared__ float cg[64][4];
    __shared__ float Plds[64][9];
    __shared__ float wl[64][68];   // w_lds[g][pixel], padded pitch
    __shared__ float Tent[64];

    const int t   = threadIdx.x;
    const int pi  = t & 63;
    const int grp = t >> 6;
    const int pq  = t & 31;
    const int og  = t >> 5;

    const int tile = blockIdx.x;          // 0..255
    const int hrow = tile >> 1;
    const int w0   = (tile & 1) * 64;

    float acc0[32], acc1[32];
    #pragma unroll
    for (int q = 0; q < 32; ++q) { acc0[q] = 0.f; acc1[q] = 0.f; }
    float col0[3] = {0.f,0.f,0.f}, col1[3] = {0.f,0.f,0.f};

    if (t < 64) Tent[t] = 1.f;

    const float gxp = (float)(w0 + pi);
    const float gyp = (float)hrow;

    for (int c = 0; c < 16; ++c) {
        __syncthreads();                       // wl/pg free, Tent visible
        pg[t>>3][t&7] = psort[c*512 + t];
        if (t < 256) cg[t>>2][t&3] = csort[c*256 + t];
        __syncthreads();

        // --- alpha phase: 8 groups x 8 gaussians per pixel ---
        float a[8];
        float Pl = 1.f;
        #pragma unroll
        for (int j = 0; j < 8; ++j) {
            int g = grp*8 + j;
            float dx = pg[g][0] - gxp;
            float dy = pg[g][1] - gyp;
            float power = -0.5f*(pg[g][2]*dx*dx + pg[g][4]*dy*dy) - pg[g][3]*dx*dy;
            float al = fminf(0.99f, pg[g][5]*__expf(power));
            bool keep = (power <= 0.f) && (al >= (1.f/255.f)) && (pg[g][7] > 0.5f);
            a[j] = keep ? al : 0.f;
            Pl *= (1.f - a[j]);
        }
        Plds[pi][grp] = Pl;
        __syncthreads();

        // --- prefix + weight emission ---
        float pref = Tent[pi];
        for (int G = 0; G < grp; ++G) pref *= Plds[pi][G];
        #pragma unroll
        for (int j = 0; j < 8; ++j) {
            wl[grp*8+j][pi] = pref * a[j];
            pref *= (1.f - a[j]);
        }
        __syncthreads();
        if (grp == 7) Tent[pi] = pref;         // next read is after top-of-loop sync

        // --- GEMM phase: acc[px][o] += w[px][g] * G[g][o] (wave-uniform skip) ---
        const float* gbase = Gv + (size_t)(c*64)*O_DIM + og*32;
        for (int g = 0; g < 64; ++g) {
            float2 wv = *reinterpret_cast<const float2*>(&wl[g][2*pq]);
            if (__ballot((wv.x != 0.f) || (wv.y != 0.f)) != 0ull) {
                const float4* gp = reinterpret_cast<const float4*>(gbase + (size_t)g*O_DIM);
                #pragma unroll
                for (int q = 0; q < 8; ++q) {
                    float4 gv = gp[q];
                    acc0[4*q+0] += wv.x*gv.x; acc0[4*q+1] += wv.x*gv.y;
                    acc0[4*q+2] += wv.x*gv.z; acc0[4*q+3] += wv.x*gv.w;
                    acc1[4*q+0] += wv.y*gv.x; acc1[4*q+1] += wv.y*gv.y;
                    acc1[4*q+2] += wv.y*gv.z; acc1[4*q+3] += wv.y*gv.w;
                }
                if (og == 0) {
                    #pragma unroll
                    for (int ch = 0; ch < 3; ++ch) {
                        col0[ch] += wv.x*cg[g][ch];
                        col1[ch] += wv.y*cg[g][ch];
                    }
                }
            }
        }
    }
    __syncthreads();

    const int pixbase = hrow*W_IMG + w0 + 2*pq;
    #pragma unroll
    for (int q = 0; q < 32; ++q) {
        int o = og*32 + q;
        float cb = conv_b[o];
        float2 v; v.x = acc0[q] + cb; v.y = acc1[q] + cb;
        *reinterpret_cast<float2*>(out + FEAT_OFF + (size_t)o*PIX + pixbase) = v;
    }
    if (og == 0) {
        float t0 = Tent[2*pq], t1 = Tent[2*pq+1];
        #pragma unroll
        for (int ch = 0; ch < 3; ++ch) {
            out[ch*PIX + pixbase]     = col0[ch] + t0*bg[ch];
            out[ch*PIX + pixbase + 1] = col1[ch] + t1*bg[ch];
        }
    }
}

// ---------------------------------------------------------------------------
extern "C" void kernel_launch(void* const* d_in, const int* in_sizes, int n_in,
                              void* d_out, int out_size, void* d_ws, size_t ws_size,
                              hipStream_t stream)
{
    const float* means  = (const float*)d_in[0];
    const float* opac   = (const float*)d_in[2];
    const float* colors = (const float*)d_in[3];
    const float* sem    = (const float*)d_in[4];
    const float* scales = (const float*)d_in[5];
    const float* rots   = (const float*)d_in[6];
    const float* view   = (const float*)d_in[7];
    const float* proj   = (const float*)d_in[8];
    const float* bg     = (const float*)d_in[9];
    const float* conv_w = (const float*)d_in[11];
    const float* conv_b = (const float*)d_in[12];
    float* out = (float*)d_out;

    float* wsf     = (float*)d_ws;
    float* params8 = wsf;                    // 1024*8
    float* psort   = wsf + 8192;             // 1024*8
    float* csort   = wsf + 16384;            // 1024*4
    int*   order   = (int*)(wsf + 20480);    // 1024
    float* Gv      = wsf + 24576;            // 1024*512

    float* radii_out = out + RAD_OFF;

    prep_kernel<<<4, 256, 0, stream>>>(means, opac, scales, rots, view, proj,
                                       params8, radii_out);
    rank_kernel<<<4, 256, 0, stream>>>(params8, order);
    pack_kernel<<<4, 256, 0, stream>>>(params8, colors, order, psort, csort);
    gmat_kernel<<<dim3(64,32), dim3(16,16), 0, stream>>>(sem, conv_w, order, Gv);
    composite_kernel<<<256, 512, 0, stream>>>(psort, csort, Gv, conv_b, bg, out);
}

// Round 2
// 198.674 us; speedup vs baseline: 1.0652x; 1.0652x over previous
//
#include <hip/hip_runtime.h>
#include <math.h>

#define H_IMG 128
#define W_IMG 128
#define N_G   1024
#define F_DIM 512
#define O_DIM 512
#define PIX   (H_IMG*W_IMG)        // 16384
#define FEAT_OFF 49152             // 3*PIX
#define RAD_OFF  (49152 + 512*16384)
#define MAXG  192                  // per-tile survivor cap (mean ~70)

// ---------------------------------------------------------------------------
// Kernel 1: per-gaussian preprocessing (projection, conic, radii)
// ---------------------------------------------------------------------------
__global__ void prep_kernel(const float* __restrict__ means,
                            const float* __restrict__ opac,
                            const float* __restrict__ scales,
                            const float* __restrict__ rots,
                            const float* __restrict__ view,
                            const float* __restrict__ proj,
                            float* __restrict__ params8,
                            float* __restrict__ radii_out)
{
    int n = blockIdx.x * blockDim.x + threadIdx.x;
    if (n >= N_G) return;

    float x = means[3*n], y = means[3*n+1], z = means[3*n+2];
    float pv0 = x*view[0] + y*view[4] + z*view[8]  + view[12];
    float pv1 = x*view[1] + y*view[5] + z*view[9]  + view[13];
    float pv2 = x*view[2] + y*view[6] + z*view[10] + view[14];
    float ph0 = x*proj[0] + y*proj[4] + z*proj[8]  + proj[12];
    float ph1 = x*proj[1] + y*proj[5] + z*proj[9]  + proj[13];
    float phw = x*proj[3] + y*proj[7] + z*proj[11] + proj[15];
    float denom = phw + 1e-7f;
    float pp0 = ph0/denom, pp1 = ph1/denom;
    float depth = pv2;

    float qr=rots[4*n], qx=rots[4*n+1], qy=rots[4*n+2], qz=rots[4*n+3];
    float qn = sqrtf(qr*qr+qx*qx+qy*qy+qz*qz);
    qr/=qn; qx/=qn; qy/=qn; qz/=qn;
    float R00=1.f-2.f*(qy*qy+qz*qz), R01=2.f*(qx*qy-qr*qz), R02=2.f*(qx*qz+qr*qy);
    float R10=2.f*(qx*qy+qr*qz), R11=1.f-2.f*(qx*qx+qz*qz), R12=2.f*(qy*qz-qr*qx);
    float R20=2.f*(qx*qz-qr*qy), R21=2.f*(qy*qz+qr*qx), R22=1.f-2.f*(qx*qx+qy*qy);
    float s0=scales[3*n], s1=scales[3*n+1], s2=scales[3*n+2];
    float M00=R00*s0, M01=R01*s1, M02=R02*s2;
    float M10=R10*s0, M11=R11*s1, M12=R12*s2;
    float M20=R20*s0, M21=R21*s1, M22=R22*s2;
    float c00=M00*M00+M01*M01+M02*M02;
    float c01=M00*M10+M01*M11+M02*M12;
    float c02=M00*M20+M01*M21+M02*M22;
    float c11=M10*M10+M11*M11+M12*M12;
    float c12=M10*M20+M11*M21+M12*M22;
    float c22=M20*M20+M21*M21+M22*M22;

    const float fx=128.f, fy=128.f;
    float tz = pv2;
    float txz = fminf(fmaxf(pv0/tz, -0.65f), 0.65f) * tz;
    float tyz = fminf(fmaxf(pv1/tz, -0.65f), 0.65f) * tz;
    float J00 = fx/tz,  J02 = -fx*txz/(tz*tz);
    float J11 = fy/tz,  J12 = -fy*tyz/(tz*tz);
    float T00=J00*view[0] + J02*view[2];
    float T01=J00*view[4] + J02*view[6];
    float T02=J00*view[8] + J02*view[10];
    float T10=J11*view[1] + J12*view[2];
    float T11=J11*view[5] + J12*view[6];
    float T12=J11*view[9] + J12*view[10];
    float u0 = T00*c00 + T01*c01 + T02*c02;
    float u1 = T00*c01 + T01*c11 + T02*c12;
    float u2 = T00*c02 + T01*c12 + T02*c22;
    float v0 = T10*c00 + T11*c01 + T12*c02;
    float v1 = T10*c01 + T11*c11 + T12*c12;
    float v2 = T10*c02 + T11*c12 + T12*c22;
    float a00 = u0*T00 + u1*T01 + u2*T02 + 0.3f;
    float a01 = u0*T10 + u1*T11 + u2*T12;
    float a11 = v0*T10 + v1*T11 + v2*T12 + 0.3f;

    float det = a00*a11 - a01*a01;
    float dsafe = (det==0.f) ? 1.f : det;
    float inv = 1.f/dsafe;
    float con0 =  a11*inv, con1 = -a01*inv, con2 = a00*inv;
    float mid = 0.5f*(a00+a11);
    float lam1 = mid + sqrtf(fmaxf(0.1f, mid*mid - det));
    int irad = (int)ceilf(3.f*sqrtf(lam1));
    float pxc = ((pp0+1.f)*128.f - 1.f)*0.5f;
    float pyc = ((pp1+1.f)*128.f - 1.f)*0.5f;
    bool valid = (depth > 0.2f) && (det != 0.f);

    radii_out[n] = valid ? (float)irad : 0.f;
    float* p = params8 + 8*n;
    p[0]=pxc; p[1]=pyc; p[2]=con0; p[3]=con1; p[4]=con2;
    p[5]=opac[n]; p[6]=depth; p[7]= valid ? 1.f : 0.f;
}

// ---------------------------------------------------------------------------
// Kernel 2: rank sort (stable argsort by depth)
// ---------------------------------------------------------------------------
__global__ void rank_kernel(const float* __restrict__ params8, int* __restrict__ order)
{
    __shared__ float d[N_G];
    int t = threadIdx.x;
    for (int i = t; i < N_G; i += 256) d[i] = params8[8*i+6];
    __syncthreads();
    int n = blockIdx.x*256 + t;
    float dn = d[n];
    int r = 0;
    for (int m = 0; m < N_G; ++m) {
        float dm = d[m];
        r += (dm < dn) || (dm == dn && m < n);
    }
    order[r] = n;
}

// ---------------------------------------------------------------------------
// Kernel 3: pack params/colors into sorted order
// ---------------------------------------------------------------------------
__global__ void pack_kernel(const float* __restrict__ params8,
                            const float* __restrict__ colors,
                            const int* __restrict__ order,
                            float* __restrict__ psort, float* __restrict__ csort)
{
    int k = blockIdx.x*256 + threadIdx.x;
    if (k >= N_G) return;
    int n = order[k];
    #pragma unroll
    for (int j = 0; j < 8; ++j) psort[8*k+j] = params8[8*n+j];
    csort[4*k+0] = colors[3*n+0];
    csort[4*k+1] = colors[3*n+1];
    csort[4*k+2] = colors[3*n+2];
    csort[4*k+3] = 0.f;
}

// ---------------------------------------------------------------------------
// Kernel 4: G[k][o] = sum_f S[order[k],f] * conv_w[o,f]
// ---------------------------------------------------------------------------
__global__ __launch_bounds__(256) void gmat_kernel(const float* __restrict__ S,
                                                   const float* __restrict__ Wm,
                                                   const int* __restrict__ order,
                                                   float* __restrict__ Gv)
{
    __shared__ float St[16][33];
    __shared__ float Wt[16][33];
    int tx = threadIdx.x, ty = threadIdx.y;
    int n0 = blockIdx.x*16, o0 = blockIdx.y*16;
    int srow = order[n0+ty];
    float acc = 0.f;
    for (int f0 = 0; f0 < F_DIM; f0 += 32) {
        St[ty][tx]    = S[(size_t)srow*F_DIM + f0+tx];
        St[ty][tx+16] = S[(size_t)srow*F_DIM + f0+tx+16];
        Wt[ty][tx]    = Wm[(size_t)(o0+ty)*F_DIM + f0+tx];
        Wt[ty][tx+16] = Wm[(size_t)(o0+ty)*F_DIM + f0+tx+16];
        __syncthreads();
        #pragma unroll
        for (int f = 0; f < 32; ++f) acc += St[ty][f]*Wt[tx][f];
        __syncthreads();
    }
    Gv[(size_t)(n0+ty)*O_DIM + o0+tx] = acc;
}

// ---------------------------------------------------------------------------
// Kernel 5: compositing weights + per-tile compaction + color output
//   256 blocks (one per 64-px strip), 512 threads: lane=pixel, wave=g-octet
// ---------------------------------------------------------------------------
__global__ __launch_bounds__(512) void weights_kernel(
    const float* __restrict__ psort, const float* __restrict__ csort,
    const float* __restrict__ bg,
    float* __restrict__ wlist, int* __restrict__ idxl, int* __restrict__ cntl,
    float* __restrict__ out)
{
    __shared__ float pg[64][8];
    __shared__ float cg[64][4];
    __shared__ float Plds[64][9];
    __shared__ float Tent[64];
    __shared__ unsigned int survb[8];
    __shared__ int slot_g[64];
    __shared__ int cnt_s;
    __shared__ float colbuf[8][64][4];

    const int t    = threadIdx.x;
    const int lane = t & 63;       // pixel in strip
    const int wv   = t >> 6;       // wave = gaussian octet

    const int tile = blockIdx.x;
    const int hrow = tile >> 1;
    const int w0   = (tile & 1) * 64;

    if (t < 64) Tent[t] = 1.f;
    if (t == 0) cnt_s = 0;

    const float gxp = (float)(w0 + lane);
    const float gyp = (float)hrow;

    float col0 = 0.f, col1 = 0.f, col2 = 0.f;

    for (int c = 0; c < 16; ++c) {
        __syncthreads();                                   // pg/cg free, Tent visible
        pg[t>>3][t&7] = psort[c*512 + t];
        if (t < 256) cg[t>>2][t&3] = csort[c*256 + t];
        __syncthreads();

        // alpha phase: this wave's 8 gaussians at this lane's pixel
        float a[8];
        float Pl = 1.f;
        #pragma unroll
        for (int j = 0; j < 8; ++j) {
            int g = wv*8 + j;
            float4 p0 = *reinterpret_cast<const float4*>(&pg[g][0]);
            float4 p1 = *reinterpret_cast<const float4*>(&pg[g][4]);
            float dx = p0.x - gxp, dy = p0.y - gyp;
            float power = -0.5f*(p0.z*dx*dx + p1.x*dy*dy) - p0.w*dx*dy;
            float al = fminf(0.99f, p1.y*__expf(power));
            bool keep = (power <= 0.f) && (al >= (1.f/255.f)) && (p1.w > 0.5f);
            a[j] = keep ? al : 0.f;
            Pl *= 1.f - a[j];
        }
        Plds[lane][wv] = Pl;
        __syncthreads();

        // prefix transmittance + weight emission (w stays in registers)
        float pref = Tent[lane];
        for (int G = 0; G < wv; ++G) pref *= Plds[lane][G];
        float w[8];
        unsigned int bits = 0;
        #pragma unroll
        for (int j = 0; j < 8; ++j) {
            w[j] = pref * a[j];
            float4 cv = *reinterpret_cast<const float4*>(&cg[wv*8+j][0]);
            col0 += w[j]*cv.x; col1 += w[j]*cv.y; col2 += w[j]*cv.z;
            pref *= 1.f - a[j];
            if (__ballot(w[j] > 1e-12f) != 0ull) bits |= (1u << j);
        }
        if (lane == 0) survb[wv] = bits;
        __syncthreads();

        if (wv == 7) Tent[lane] = pref;    // read next chunk after 2 more barriers

        // deterministic slot assignment (wave 0, depth order preserved)
        if (t < 64) {
            int flag = (survb[t>>3] >> (t&7)) & 1;
            unsigned long long m = __ballot(flag != 0);
            int base = cnt_s;                                  // lockstep read-before-write
            int rank = (int)__popcll(m & ((1ull << t) - 1ull));
            int sl = base + rank;
            slot_g[t] = (flag && sl < MAXG) ? sl : -1;
            if (t == 0) cnt_s = base + (int)__popcll(m);
        }
        __syncthreads();

        // write surviving weight rows
        #pragma unroll
        for (int j = 0; j < 8; ++j) {
            int g = wv*8 + j;
            int sl = slot_g[g];
            if (sl >= 0) {
                wlist[((size_t)tile*MAXG + sl)*64 + lane] = w[j];
                if (lane == 0) idxl[tile*MAXG + sl] = c*64 + g;
            }
        }
    }

    // color epilogue
    colbuf[wv][lane][0] = col0; colbuf[wv][lane][1] = col1; colbuf[wv][lane][2] = col2;
    __syncthreads();
    if (t < 64) {
        float r = 0.f, g = 0.f, b = 0.f;
        #pragma unroll
        for (int k = 0; k < 8; ++k) {
            r += colbuf[k][t][0]; g += colbuf[k][t][1]; b += colbuf[k][t][2];
        }
        float Tf = Tent[t];
        int pix = hrow*W_IMG + w0 + t;
        out[0*PIX + pix] = r + Tf*bg[0];
        out[1*PIX + pix] = g + Tf*bg[1];
        out[2*PIX + pix] = b + Tf*bg[2];
    }
    if (t == 0) cntl[tile] = (cnt_s < MAXG) ? cnt_s : MAXG;
}

// ---------------------------------------------------------------------------
// Kernel 6: per-tile feature GEMM over compacted survivors
//   grid (4 ochunks, 256 tiles), 256 threads: px = t&63, og = t>>6
// ---------------------------------------------------------------------------
__global__ __launch_bounds__(256) void featgemm_kernel(
    const float* __restrict__ wlist, const int* __restrict__ idxl,
    const int* __restrict__ cntl, const float* __restrict__ Gv,
    const float* __restrict__ conv_b, float* __restrict__ out)
{
    const int t  = threadIdx.x;
    const int px = t & 63;
    const int og = t >> 6;                       // 0..3
    const int tile = blockIdx.y;
    const int o0 = blockIdx.x*128 + og*32;

    const int cnt = cntl[tile];
    const float* wb = wlist + (size_t)tile*MAXG*64;
    const int*   ib = idxl + tile*MAXG;

    float acc[32];
    #pragma unroll
    for (int q = 0; q < 32; ++q) acc[q] = 0.f;

    int s = 0;
    for (; s + 2 <= cnt; s += 2) {
        float wa = wb[s*64 + px];
        float wc = wb[(s+1)*64 + px];
        int ga = ib[s];
        int gc = ib[s+1];
        const float4* gpa = reinterpret_cast<const float4*>(Gv + (size_t)ga*O_DIM + o0);
        const float4* gpc = reinterpret_cast<const float4*>(Gv + (size_t)gc*O_DIM + o0);
        #pragma unroll
        for (int q = 0; q < 8; ++q) {
            float4 va = gpa[q];
            acc[4*q+0] += wa*va.x; acc[4*q+1] += wa*va.y;
            acc[4*q+2] += wa*va.z; acc[4*q+3] += wa*va.w;
        }
        #pragma unroll
        for (int q = 0; q < 8; ++q) {
            float4 vc = gpc[q];
            acc[4*q+0] += wc*vc.x; acc[4*q+1] += wc*vc.y;
            acc[4*q+2] += wc*vc.z; acc[4*q+3] += wc*vc.w;
        }
    }
    if (s < cnt) {
        float wa = wb[s*64 + px];
        int ga = ib[s];
        const float4* gpa = reinterpret_cast<const float4*>(Gv + (size_t)ga*O_DIM + o0);
        #pragma unroll
        for (int q = 0; q < 8; ++q) {
            float4 va = gpa[q];
            acc[4*q+0] += wa*va.x; acc[4*q+1] += wa*va.y;
            acc[4*q+2] += wa*va.z; acc[4*q+3] += wa*va.w;
        }
    }

    const int pix = (tile >> 1)*W_IMG + (tile & 1)*64 + px;
    #pragma unroll
    for (int q = 0; q < 32; ++q) {
        out[FEAT_OFF + (size_t)(o0+q)*PIX + pix] = acc[q] + conv_b[o0+q];
    }
}

// ---------------------------------------------------------------------------
extern "C" void kernel_launch(void* const* d_in, const int* in_sizes, int n_in,
                              void* d_out, int out_size, void* d_ws, size_t ws_size,
                              hipStream_t stream)
{
    const float* means  = (const float*)d_in[0];
    const float* opac   = (const float*)d_in[2];
    const float* colors = (const float*)d_in[3];
    const float* sem    = (const float*)d_in[4];
    const float* scales = (const float*)d_in[5];
    const float* rots   = (const float*)d_in[6];
    const float* view   = (const float*)d_in[7];
    const float* proj   = (const float*)d_in[8];
    const float* bg     = (const float*)d_in[9];
    const float* conv_w = (const float*)d_in[11];
    const float* conv_b = (const float*)d_in[12];
    float* out = (float*)d_out;

    float* wsf     = (float*)d_ws;
    float* params8 = wsf;                    // 8192 floats
    float* psort   = wsf + 8192;             // 8192
    float* csort   = wsf + 16384;            // 4096
    int*   order   = (int*)(wsf + 20480);    // 1024
    int*   cntl    = (int*)(wsf + 21504);    // 256
    float* Gv      = wsf + 24576;            // 1024*512
    int*   idxl    = (int*)(wsf + 548864);   // 256*192
    float* wlist   = wsf + 598016;           // 256*192*64 -> ends ~15 MB

    float* radii_out = out + RAD_OFF;

    prep_kernel<<<4, 256, 0, stream>>>(means, opac, scales, rots, view, proj,
                                       params8, radii_out);
    rank_kernel<<<4, 256, 0, stream>>>(params8, order);
    pack_kernel<<<4, 256, 0, stream>>>(params8, colors, order, psort, csort);
    gmat_kernel<<<dim3(64,32), dim3(16,16), 0, stream>>>(sem, conv_w, order, Gv);
    weights_kernel<<<256, 512, 0, stream>>>(psort, csort, bg, wlist, idxl, cntl, out);
    featgemm_kernel<<<dim3(4,256), 256, 0, stream>>>(wlist, idxl, cntl, Gv, conv_b, out);
}

// Round 3
// 174.974 us; speedup vs baseline: 1.2095x; 1.1354x over previous
//
#include <hip/hip_runtime.h>
#include <hip/hip_bf16.h>
#include <math.h>

#define H_IMG 128
#define W_IMG 128
#define N_G   1024
#define F_DIM 512
#define O_DIM 512
#define PIX   (H_IMG*W_IMG)        // 16384
#define FEAT_OFF 49152             // 3*PIX
#define RAD_OFF  (49152 + 512*16384)
#define MAXG  192                  // per-tile survivor cap (mean ~70, validated r2)

// ---------------------------------------------------------------------------
// Kernel 1: per-gaussian preprocessing (projection, conic, radii)
// ---------------------------------------------------------------------------
__global__ void prep_kernel(const float* __restrict__ means,
                            const float* __restrict__ opac,
                            const float* __restrict__ scales,
                            const float* __restrict__ rots,
                            const float* __restrict__ view,
                            const float* __restrict__ proj,
                            float* __restrict__ params8,
                            float* __restrict__ radii_out)
{
    int n = blockIdx.x * blockDim.x + threadIdx.x;
    if (n >= N_G) return;

    float x = means[3*n], y = means[3*n+1], z = means[3*n+2];
    float pv0 = x*view[0] + y*view[4] + z*view[8]  + view[12];
    float pv1 = x*view[1] + y*view[5] + z*view[9]  + view[13];
    float pv2 = x*view[2] + y*view[6] + z*view[10] + view[14];
    float ph0 = x*proj[0] + y*proj[4] + z*proj[8]  + proj[12];
    float ph1 = x*proj[1] + y*proj[5] + z*proj[9]  + proj[13];
    float phw = x*proj[3] + y*proj[7] + z*proj[11] + proj[15];
    float denom = phw + 1e-7f;
    float pp0 = ph0/denom, pp1 = ph1/denom;
    float depth = pv2;

    float qr=rots[4*n], qx=rots[4*n+1], qy=rots[4*n+2], qz=rots[4*n+3];
    float qn = sqrtf(qr*qr+qx*qx+qy*qy+qz*qz);
    qr/=qn; qx/=qn; qy/=qn; qz/=qn;
    float R00=1.f-2.f*(qy*qy+qz*qz), R01=2.f*(qx*qy-qr*qz), R02=2.f*(qx*qz+qr*qy);
    float R10=2.f*(qx*qy+qr*qz), R11=1.f-2.f*(qx*qx+qz*qz), R12=2.f*(qy*qz-qr*qx);
    float R20=2.f*(qx*qz-qr*qy), R21=2.f*(qy*qz+qr*qx), R22=1.f-2.f*(qx*qx+qy*qy);
    float s0=scales[3*n], s1=scales[3*n+1], s2=scales[3*n+2];
    float M00=R00*s0, M01=R01*s1, M02=R02*s2;
    float M10=R10*s0, M11=R11*s1, M12=R12*s2;
    float M20=R20*s0, M21=R21*s1, M22=R22*s2;
    float c00=M00*M00+M01*M01+M02*M02;
    float c01=M00*M10+M01*M11+M02*M12;
    float c02=M00*M20+M01*M21+M02*M22;
    float c11=M10*M10+M11*M11+M12*M12;
    float c12=M10*M20+M11*M21+M12*M22;
    float c22=M20*M20+M21*M21+M22*M22;

    const float fx=128.f, fy=128.f;
    float tz = pv2;
    float txz = fminf(fmaxf(pv0/tz, -0.65f), 0.65f) * tz;
    float tyz = fminf(fmaxf(pv1/tz, -0.65f), 0.65f) * tz;
    float J00 = fx/tz,  J02 = -fx*txz/(tz*tz);
    float J11 = fy/tz,  J12 = -fy*tyz/(tz*tz);
    float T00=J00*view[0] + J02*view[2];
    float T01=J00*view[4] + J02*view[6];
    float T02=J00*view[8] + J02*view[10];
    float T10=J11*view[1] + J12*view[2];
    float T11=J11*view[5] + J12*view[6];
    float T12=J11*view[9] + J12*view[10];
    float u0 = T00*c00 + T01*c01 + T02*c02;
    float u1 = T00*c01 + T01*c11 + T02*c12;
    float u2 = T00*c02 + T01*c12 + T02*c22;
    float v0 = T10*c00 + T11*c01 + T12*c02;
    float v1 = T10*c01 + T11*c11 + T12*c12;
    float v2 = T10*c02 + T11*c12 + T12*c22;
    float a00 = u0*T00 + u1*T01 + u2*T02 + 0.3f;
    float a01 = u0*T10 + u1*T11 + u2*T12;
    float a11 = v0*T10 + v1*T11 + v2*T12 + 0.3f;

    float det = a00*a11 - a01*a01;
    float dsafe = (det==0.f) ? 1.f : det;
    float inv = 1.f/dsafe;
    float con0 =  a11*inv, con1 = -a01*inv, con2 = a00*inv;
    float mid = 0.5f*(a00+a11);
    float lam1 = mid + sqrtf(fmaxf(0.1f, mid*mid - det));
    int irad = (int)ceilf(3.f*sqrtf(lam1));
    float pxc = ((pp0+1.f)*128.f - 1.f)*0.5f;
    float pyc = ((pp1+1.f)*128.f - 1.f)*0.5f;
    bool valid = (depth > 0.2f) && (det != 0.f);

    radii_out[n] = valid ? (float)irad : 0.f;
    float* p = params8 + 8*n;
    p[0]=pxc; p[1]=pyc; p[2]=con0; p[3]=con1; p[4]=con2;
    p[5]=opac[n]; p[6]=depth; p[7]= valid ? 1.f : 0.f;
}

// ---------------------------------------------------------------------------
// Kernel 2: rank sort (stable argsort by depth)
// ---------------------------------------------------------------------------
__global__ void rank_kernel(const float* __restrict__ params8, int* __restrict__ order)
{
    __shared__ float d[N_G];
    int t = threadIdx.x;
    for (int i = t; i < N_G; i += 256) d[i] = params8[8*i+6];
    __syncthreads();
    int n = blockIdx.x*256 + t;
    float dn = d[n];
    int r = 0;
    for (int m = 0; m < N_G; ++m) {
        float dm = d[m];
        r += (dm < dn) || (dm == dn && m < n);
    }
    order[r] = n;
}

// ---------------------------------------------------------------------------
// Kernel 3: pack params/colors into sorted order
// ---------------------------------------------------------------------------
__global__ void pack_kernel(const float* __restrict__ params8,
                            const float* __restrict__ colors,
                            const int* __restrict__ order,
                            float* __restrict__ psort, float* __restrict__ csort)
{
    int k = blockIdx.x*256 + threadIdx.x;
    if (k >= N_G) return;
    int n = order[k];
    #pragma unroll
    for (int j = 0; j < 8; ++j) psort[8*k+j] = params8[8*n+j];
    csort[4*k+0] = colors[3*n+0];
    csort[4*k+1] = colors[3*n+1];
    csort[4*k+2] = colors[3*n+2];
    csort[4*k+3] = 0.f;
}

// ---------------------------------------------------------------------------
// Kernel 4: G[k][o] = sum_f S[order[k],f] * conv_w[o,f]
// ---------------------------------------------------------------------------
__global__ __launch_bounds__(256) void gmat_kernel(const float* __restrict__ S,
                                                   const float* __restrict__ Wm,
                                                   const int* __restrict__ order,
                                                   float* __restrict__ Gv)
{
    __shared__ float St[16][33];
    __shared__ float Wt[16][33];
    int tx = threadIdx.x, ty = threadIdx.y;
    int n0 = blockIdx.x*16, o0 = blockIdx.y*16;
    int srow = order[n0+ty];
    float acc = 0.f;
    for (int f0 = 0; f0 < F_DIM; f0 += 32) {
        St[ty][tx]    = S[(size_t)srow*F_DIM + f0+tx];
        St[ty][tx+16] = S[(size_t)srow*F_DIM + f0+tx+16];
        Wt[ty][tx]    = Wm[(size_t)(o0+ty)*F_DIM + f0+tx];
        Wt[ty][tx+16] = Wm[(size_t)(o0+ty)*F_DIM + f0+tx+16];
        __syncthreads();
        #pragma unroll
        for (int f = 0; f < 32; ++f) acc += St[ty][f]*Wt[tx][f];
        __syncthreads();
    }
    Gv[(size_t)(n0+ty)*O_DIM + o0+tx] = acc;
}

// ---------------------------------------------------------------------------
// Kernel 5: alpha/compositing. One block per 64-px strip, 16 waves = 16
// independent 64-gaussian chunks. Two barriers total. Emits compacted,
// depth-ordered, FINAL (cross-chunk scaled) bf16 weight rows + color image.
// ---------------------------------------------------------------------------
__global__ __launch_bounds__(1024) void alpha_kernel(
    const float* __restrict__ psort, const float* __restrict__ csort,
    const float* __restrict__ bg,
    __hip_bfloat16* __restrict__ wbuf, int* __restrict__ idxl,
    int* __restrict__ cnttot, float* __restrict__ out)
{
    __shared__ float pg[N_G][8];        // 32 KB: all sorted params
    __shared__ float cs[N_G][4];        // 16 KB: all sorted colors
    __shared__ float Pl[16][64];        // per-chunk per-px transmittance
    __shared__ float colbuf[16][64][4]; // 16 KB
    __shared__ float Tfl[64];
    __shared__ int   cntl_s[16];

    const int t    = threadIdx.x;
    const int c    = t >> 6;        // chunk / wave
    const int lane = t & 63;        // pixel in strip
    const int tile = blockIdx.x;
    const int hrow = tile >> 1;
    const int w0   = (tile & 1) * 64;

    // stage all params + colors (coalesced)
    {
        float4* pgv = reinterpret_cast<float4*>(&pg[0][0]);
        const float4* ps4 = reinterpret_cast<const float4*>(psort);
        pgv[t]        = ps4[t];
        pgv[t + 1024] = ps4[t + 1024];
        float4* csv = reinterpret_cast<float4*>(&cs[0][0]);
        csv[t] = reinterpret_cast<const float4*>(csort)[t];
    }
    __syncthreads();

    const float gx = (float)(w0 + lane);
    const float gy = (float)hrow;

    // ---- pass 1: per-chunk transmittance + survivor count (no barriers) ----
    float pref = 1.f;
    int cnt = 0;
    for (int j = 0; j < 64; ++j) {
        int g = c*64 + j;
        float4 A = *reinterpret_cast<const float4*>(&pg[g][0]);
        float4 B = *reinterpret_cast<const float4*>(&pg[g][4]);
        float dx = A.x - gx, dy = A.y - gy;
        float pw = -0.5f*(A.z*dx*dx + B.x*dy*dy) - A.w*dx*dy;
        float al = fminf(0.99f, B.y*__expf(pw));
        bool keep = (pw <= 0.f) && (al >= (1.f/255.f)) && (B.w > 0.5f);
        float a = keep ? al : 0.f;
        float w = pref * a;
        pref *= 1.f - a;
        cnt += (__ballot(w > 1e-12f) != 0ull) ? 1 : 0;
    }
    Pl[c][lane] = pref;
    if (lane == 0) cntl_s[c] = cnt;
    __syncthreads();

    // cross-chunk prefix: slot base + transmittance prefix (per lane)
    int base = 0;
    float cp = 1.f;
    for (int cc = 0; cc < c; ++cc) {
        base += cntl_s[cc];
        cp *= Pl[cc][lane];
    }
    if (c == 15) {
        Tfl[lane] = cp * Pl[15][lane];
        if (lane == 0) {
            int tot = base + cntl_s[15];
            cnttot[tile] = (tot < MAXG) ? tot : MAXG;
        }
    }

    // ---- pass 2: recompute alphas, write final bf16 weights + color ----
    float pref2 = 1.f;
    int slot = base;
    float col0 = 0.f, col1 = 0.f, col2 = 0.f;
    for (int j = 0; j < 64; ++j) {
        int g = c*64 + j;
        float4 A = *reinterpret_cast<const float4*>(&pg[g][0]);
        float4 B = *reinterpret_cast<const float4*>(&pg[g][4]);
        float dx = A.x - gx, dy = A.y - gy;
        float pw = -0.5f*(A.z*dx*dx + B.x*dy*dy) - A.w*dx*dy;
        float al = fminf(0.99f, B.y*__expf(pw));
        bool keep = (pw <= 0.f) && (al >= (1.f/255.f)) && (B.w > 0.5f);
        float a = keep ? al : 0.f;
        float w = pref2 * a;
        pref2 *= 1.f - a;
        if (__ballot(w > 1e-12f) != 0ull) {
            float wfin = w * cp;
            if (slot < MAXG) {
                wbuf[((size_t)tile*MAXG + slot)*64 + lane] = __float2bfloat16(wfin);
                if (lane == 0) idxl[tile*MAXG + slot] = g;
            }
            float4 cv = *reinterpret_cast<const float4*>(&cs[g][0]);
            col0 += wfin*cv.x; col1 += wfin*cv.y; col2 += wfin*cv.z;
            ++slot;
        }
    }

    colbuf[c][lane][0] = col0; colbuf[c][lane][1] = col1; colbuf[c][lane][2] = col2;
    __syncthreads();

    if (t < 64) {
        float r = 0.f, g = 0.f, b = 0.f;
        #pragma unroll
        for (int k = 0; k < 16; ++k) {
            r += colbuf[k][t][0]; g += colbuf[k][t][1]; b += colbuf[k][t][2];
        }
        float Tf = Tfl[t];
        int pix = hrow*W_IMG + w0 + t;
        out[0*PIX + pix] = r + Tf*bg[0];
        out[1*PIX + pix] = g + Tf*bg[1];
        out[2*PIX + pix] = b + Tf*bg[2];
    }
}

// ---------------------------------------------------------------------------
// Kernel 6: per-tile feature GEMM. grid (8 o-slices, 256 tiles), 256 threads.
// px = t&63, og = t>>6 (4 groups x 16 outputs). Weights pre-scaled bf16.
// ---------------------------------------------------------------------------
__global__ __launch_bounds__(256) void featgemm_kernel(
    const __hip_bfloat16* __restrict__ wbuf, const int* __restrict__ idxl,
    const int* __restrict__ cnttot, const float* __restrict__ Gv,
    const float* __restrict__ conv_b, float* __restrict__ out)
{
    const int t    = threadIdx.x;
    const int px   = t & 63;
    const int og   = t >> 6;                 // 0..3
    const int tile = blockIdx.y;
    const int o0   = blockIdx.x*64 + og*16;

    const int cnt = cnttot[tile];
    const __hip_bfloat16* wb = wbuf + (size_t)tile*MAXG*64;
    const int* ib = idxl + tile*MAXG;

    float acc[16];
    #pragma unroll
    for (int q = 0; q < 16; ++q) acc[q] = 0.f;

    int s = 0;
    for (; s + 4 <= cnt; s += 4) {
        float w0 = __bfloat162float(wb[(s+0)*64 + px]);
        float w1 = __bfloat162float(wb[(s+1)*64 + px]);
        float w2 = __bfloat162float(wb[(s+2)*64 + px]);
        float w3 = __bfloat162float(wb[(s+3)*64 + px]);
        int g0 = ib[s+0], g1 = ib[s+1], g2 = ib[s+2], g3 = ib[s+3];
        const float4* p0 = reinterpret_cast<const float4*>(Gv + (size_t)g0*O_DIM + o0);
        const float4* p1 = reinterpret_cast<const float4*>(Gv + (size_t)g1*O_DIM + o0);
        const float4* p2 = reinterpret_cast<const float4*>(Gv + (size_t)g2*O_DIM + o0);
        const float4* p3 = reinterpret_cast<const float4*>(Gv + (size_t)g3*O_DIM + o0);
        #pragma unroll
        for (int q = 0; q < 4; ++q) {
            float4 v = p0[q];
            acc[4*q+0] += w0*v.x; acc[4*q+1] += w0*v.y;
            acc[4*q+2] += w0*v.z; acc[4*q+3] += w0*v.w;
        }
        #pragma unroll
        for (int q = 0; q < 4; ++q) {
            float4 v = p1[q];
            acc[4*q+0] += w1*v.x; acc[4*q+1] += w1*v.y;
            acc[4*q+2] += w1*v.z; acc[4*q+3] += w1*v.w;
        }
        #pragma unroll
        for (int q = 0; q < 4; ++q) {
            float4 v = p2[q];
            acc[4*q+0] += w2*v.x; acc[4*q+1] += w2*v.y;
            acc[4*q+2] += w2*v.z; acc[4*q+3] += w2*v.w;
        }
        #pragma unroll
        for (int q = 0; q < 4; ++q) {
            float4 v = p3[q];
            acc[4*q+0] += w3*v.x; acc[4*q+1] += w3*v.y;
            acc[4*q+2] += w3*v.z; acc[4*q+3] += w3*v.w;
        }
    }
    for (; s < cnt; ++s) {
        float w = __bfloat162float(wb[s*64 + px]);
        int g = ib[s];
        const float4* p = reinterpret_cast<const float4*>(Gv + (size_t)g*O_DIM + o0);
        #pragma unroll
        for (int q = 0; q < 4; ++q) {
            float4 v = p[q];
            acc[4*q+0] += w*v.x; acc[4*q+1] += w*v.y;
            acc[4*q+2] += w*v.z; acc[4*q+3] += w*v.w;
        }
    }

    const int pix = (tile >> 1)*W_IMG + (tile & 1)*64 + px;
    #pragma unroll
    for (int q = 0; q < 16; ++q) {
        out[FEAT_OFF + (size_t)(o0+q)*PIX + pix] = acc[q] + conv_b[o0+q];
    }
}

// ---------------------------------------------------------------------------
extern "C" void kernel_launch(void* const* d_in, const int* in_sizes, int n_in,
                              void* d_out, int out_size, void* d_ws, size_t ws_size,
                              hipStream_t stream)
{
    const float* means  = (const float*)d_in[0];
    const float* opac   = (const float*)d_in[2];
    const float* colors = (const float*)d_in[3];
    const float* sem    = (const float*)d_in[4];
    const float* scales = (const float*)d_in[5];
    const float* rots   = (const float*)d_in[6];
    const float* view   = (const float*)d_in[7];
    const float* proj   = (const float*)d_in[8];
    const float* bg     = (const float*)d_in[9];
    const float* conv_w = (const float*)d_in[11];
    const float* conv_b = (const float*)d_in[12];
    float* out = (float*)d_out;

    float* wsf     = (float*)d_ws;
    float* params8 = wsf;                    // 8192 floats
    float* psort   = wsf + 8192;             // 8192
    float* csort   = wsf + 16384;            // 4096
    int*   order   = (int*)(wsf + 20480);    // 1024
    int*   cnttot  = (int*)(wsf + 21504);    // 256
    float* Gv      = wsf + 24576;            // 1024*512
    int*   idxl    = (int*)(wsf + 548864);   // 256*192
    __hip_bfloat16* wbuf = (__hip_bfloat16*)(wsf + 598016); // 256*192*64 bf16 (~6.3MB)

    float* radii_out = out + RAD_OFF;

    prep_kernel<<<4, 256, 0, stream>>>(means, opac, scales, rots, view, proj,
                                       params8, radii_out);
    rank_kernel<<<4, 256, 0, stream>>>(params8, order);
    pack_kernel<<<4, 256, 0, stream>>>(params8, colors, order, psort, csort);
    gmat_kernel<<<dim3(64,32), dim3(16,16), 0, stream>>>(sem, conv_w, order, Gv);
    alpha_kernel<<<256, 1024, 0, stream>>>(psort, csort, bg, wbuf, idxl, cnttot, out);
    featgemm_kernel<<<dim3(8,256), 256, 0, stream>>>(wbuf, idxl, cnttot, Gv, conv_b, out);
}